// Round 3
// baseline (2327.936 us; speedup 1.0000x reference)
//
#include <hip/hip_runtime.h>
#include <hip/hip_bf16.h>
#include <math.h>

// Problem constants (ViT): B=8, C=3, H=384, P=16 -> 24x24=576 patches, S=577
#define BB 8
#define CC 3
#define HH 384
#define PP 16
#define HP 24            // H/P
#define NP 576           // patches per image
#define PD 768           // patch dim = C*P*P
#define DIM 768
#define DEPTH 8
#define HEADS 12
#define DH 64            // DIM/HEADS
#define MLP 3072
#define SS 577           // seq len = NP+1
#define BS (BB*SS)       // 4616 rows
#define MPAD 4736        // 37*128, padded row count for GEMM A-operands
#define LN_EPS 1e-5f
#define NKT 10           // ceil(577/64) key tiles
#define QW (3*DIM)       // qkv row width 2304

typedef __attribute__((ext_vector_type(8))) short s8v;   // 8 bf16 = 4 VGPRs
typedef __attribute__((ext_vector_type(4))) float f4v;   // MFMA accum

__device__ __forceinline__ float bf2f(unsigned short s) {
    union { unsigned u; float f; } x;
    x.u = ((unsigned)s) << 16;
    return x.f;
}
__device__ __forceinline__ unsigned short f2bfu(float f) {
    __hip_bfloat16 h = __float2bfloat16(f);
    return *reinterpret_cast<unsigned short*>(&h);
}

// async global->LDS, 16B per lane; LDS dest = base + lane*16 (wave-uniform base)
__device__ __forceinline__ void async16(void* lds, const void* g) {
    __builtin_amdgcn_global_load_lds(
        (const __attribute__((address_space(1))) void*)(uintptr_t)g,
        (__attribute__((address_space(3))) void*)(unsigned)(uintptr_t)lds,
        16, 0, 0);
}

// ---------------------------------------------------------------------------
// Patchify: img (B,C,H,H) -> Xp_bf (B*NP, PD) bf16, vec index (p1*P+p2)*C + c
// ---------------------------------------------------------------------------
__global__ __launch_bounds__(256) void patchify_k(const float* __restrict__ img,
                                                  unsigned short* __restrict__ xp) {
    int idx = blockIdx.x * 256 + threadIdx.x;
    const int total = BB * NP * PD;
    if (idx >= total) return;
    int b = idx / (NP * PD);
    int r = idx % (NP * PD);
    int n = r / PD;
    int j = r % PD;
    int c  = j % CC;
    int t  = j / CC;
    int p2 = t % PP;
    int p1 = t / PP;
    int hh = n / HP;
    int ww = n % HP;
    int row = hh * PP + p1;
    int col = ww * PP + p2;
    xp[idx] = f2bfu(img[(((size_t)b * CC + c) * HH + row) * HH + col]);
}

// ---------------------------------------------------------------------------
// Weight convert + transpose: W (K,N) fp32 -> Wt (N,K) bf16.  K,N % 32 == 0.
// ---------------------------------------------------------------------------
__global__ __launch_bounds__(256) void convT_k(const float* __restrict__ W,
                                               unsigned short* __restrict__ Wt,
                                               int K, int N) {
    __shared__ float t[32][33];
    int tx = threadIdx.x & 31, ty = threadIdx.x >> 5;   // 32 x 8
    int n0 = blockIdx.x * 32, k0 = blockIdx.y * 32;
#pragma unroll
    for (int i = 0; i < 32; i += 8)
        t[ty + i][tx] = W[(size_t)(k0 + ty + i) * N + n0 + tx];
    __syncthreads();
#pragma unroll
    for (int i = 0; i < 32; i += 8)
        Wt[(size_t)(n0 + ty + i) * K + k0 + tx] = f2bfu(t[tx][ty + i]);
}

// ---------------------------------------------------------------------------
// Fused per-layer weight conversion: all 4 weights of one layer in one launch.
// Tile ranges (32x32 tiles): qkv (768,2304)=1728, out (768,768)=576,
// ff1 (768,3072)=2304, ff2 (3072,768)=2304 -> 6912 blocks total.
// ---------------------------------------------------------------------------
__global__ __launch_bounds__(256) void convT4_k(const float* __restrict__ s0,
                                                const float* __restrict__ s1,
                                                const float* __restrict__ s2,
                                                const float* __restrict__ s3,
                                                unsigned short* __restrict__ d0,
                                                unsigned short* __restrict__ d1,
                                                unsigned short* __restrict__ d2,
                                                unsigned short* __restrict__ d3) {
    __shared__ float t[32][33];
    int bid = blockIdx.x;
    const float* S; unsigned short* D; int K, N, lt;
    if (bid < 1728)      { S = s0; D = d0; K = 768;  N = 2304; lt = bid; }
    else if (bid < 2304) { S = s1; D = d1; K = 768;  N = 768;  lt = bid - 1728; }
    else if (bid < 4608) { S = s2; D = d2; K = 768;  N = 3072; lt = bid - 2304; }
    else                 { S = s3; D = d3; K = 3072; N = 768;  lt = bid - 4608; }
    int ntn = N >> 5;
    int n0 = (lt % ntn) * 32, k0 = (lt / ntn) * 32;
    int tx = threadIdx.x & 31, ty = threadIdx.x >> 5;   // 32 x 8
#pragma unroll
    for (int i = 0; i < 32; i += 8)
        t[ty + i][tx] = S[(size_t)(k0 + ty + i) * N + n0 + tx];
    __syncthreads();
#pragma unroll
    for (int i = 0; i < 32; i += 8)
        D[(size_t)(n0 + ty + i) * K + k0 + tx] = f2bfu(t[tx][ty + i]);
}

// ---------------------------------------------------------------------------
// Build residual stream x (B,S,DIM) fp32
// ---------------------------------------------------------------------------
__global__ __launch_bounds__(256) void build_x_k(const float* __restrict__ pe,
                                                 const float* __restrict__ cls,
                                                 const float* __restrict__ pos,
                                                 float* __restrict__ x) {
    int idx = blockIdx.x * 256 + threadIdx.x;
    const int total = BB * SS * DIM;
    if (idx >= total) return;
    int b = idx / (SS * DIM);
    int r = idx % (SS * DIM);
    int i = r / DIM;
    int d = r % DIM;
    float p = pos[i * DIM + d];
    float v = (i == 0) ? cls[d] : pe[((size_t)b * NP + (i - 1)) * DIM + d];
    x[idx] = v + p;
}

// ---------------------------------------------------------------------------
// LayerNorm (+ optional partial-sum residual add): one block per row.
// NPART==0: y = LN(x)            (x untouched)
// NPART==2: xn = x + P[0] + P[1]; store xn to x; y = LN(xn)
// NPART==4: xn = x + P[0..1] + P2[0..1]; store xn; y = LN(xn)
// Slice stride within a partial buffer is BS*DIM floats.
// ---------------------------------------------------------------------------
template <int NPART>
__global__ __launch_bounds__(256) void ln_k(const float* __restrict__ x,
                                            const float* __restrict__ P,
                                            const float* __restrict__ P2,
                                            const float* __restrict__ g,
                                            const float* __restrict__ bt,
                                            unsigned short* __restrict__ y,
                                            float* __restrict__ xout) {
    __shared__ float sm[8];
    int row = blockIdx.x, tid = threadIdx.x;
    const float* xr = x + (size_t)row * DIM;
    float v0 = xr[tid], v1 = xr[tid + 256], v2 = xr[tid + 512];
    if (NPART >= 2) {
        const float* p0 = P + (size_t)row * DIM;
        const float* p1 = P + (size_t)(BS + row) * DIM;
        v0 += p0[tid]       + p1[tid];
        v1 += p0[tid + 256] + p1[tid + 256];
        v2 += p0[tid + 512] + p1[tid + 512];
        if (NPART == 4) {
            const float* p2 = P2 + (size_t)row * DIM;
            const float* p3 = P2 + (size_t)(BS + row) * DIM;
            v0 += p2[tid]       + p3[tid];
            v1 += p2[tid + 256] + p3[tid + 256];
            v2 += p2[tid + 512] + p3[tid + 512];
        }
        float* xo = xout + (size_t)row * DIM;
        xo[tid] = v0; xo[tid + 256] = v1; xo[tid + 512] = v2;
    }
    float s = v0 + v1 + v2;
    for (int o = 32; o; o >>= 1) s += __shfl_xor(s, o);
    if ((tid & 63) == 0) sm[tid >> 6] = s;
    __syncthreads();
    float mean = (sm[0] + sm[1] + sm[2] + sm[3]) * (1.f / 768.f);
    float q0 = v0 - mean, q1 = v1 - mean, q2 = v2 - mean;
    float s2 = q0 * q0 + q1 * q1 + q2 * q2;
    for (int o = 32; o; o >>= 1) s2 += __shfl_xor(s2, o);
    if ((tid & 63) == 0) sm[4 + (tid >> 6)] = s2;
    __syncthreads();
    float var = (sm[4] + sm[5] + sm[6] + sm[7]) * (1.f / 768.f);
    float rstd = rsqrtf(var + LN_EPS);
    unsigned short* yr = y + (size_t)row * DIM;
    yr[tid]       = f2bfu(q0 * rstd * g[tid]       + bt[tid]);
    yr[tid + 256] = f2bfu(q1 * rstd * g[tid + 256] + bt[tid + 256]);
    yr[tid + 512] = f2bfu(q2 * rstd * g[tid + 512] + bt[tid + 512]);
}

// ---------------------------------------------------------------------------
// bf16 MFMA GEMM v4: fragment-major LDS (conflict-free ds_read: lane l's
// MFMA fragment sits at LDS base+l*16, exactly where global_load_lds's
// linear lane-ordered write puts it when the GLOBAL source address is
// fragment-mapped: row=l&15, kchunk=l>>4). 3-buffer counted-vmcnt pipeline,
// setprio around MFMA cluster, m204 bijective XCD swizzle (A-panel L2
// locality: consecutive work-ids share the A row-panel and land on one XCD).
//   A:  (Mpad, K) bf16 row-major; Bt: (N, K) bf16 row-major
//   OP 0: bf16 out = acc + bias      (bias may be null)
//   OP 1: bf16 out = gelu(acc+bias)
//   OP 2: fp32 C += acc + bias
//   OP 3: fp32 out = acc + bias
//   OP 4: fp32 partial store: slice z -> (z<2 ? Cv : Cv2) + (z&1)*M*N
// 128x128 tile, 256 thr (4 waves, 2x2), 16x16x32 MFMA, BK=32.
// ---------------------------------------------------------------------------
template <int OP, int SPLIT>
__global__ __launch_bounds__(256) void mgemm_k(const unsigned short* __restrict__ A,
                                               const unsigned short* __restrict__ Bt,
                                               const float* __restrict__ bias,
                                               void* __restrict__ Cv,
                                               void* __restrict__ Cv2,
                                               int M, int N, int K) {
    __shared__ unsigned short Al[3][128 * 32];
    __shared__ unsigned short Bl[3][128 * 32];
    int tid = threadIdx.x;
    int wv = tid >> 6, lane = tid & 63;
    int quad = lane >> 4, l16 = lane & 15;

    // m204 bijective XCD swizzle within a z-slice: blocks with the same
    // (p & 7) sit on the same XCD (hw dispatch round-robins x-fastest);
    // give each such set a contiguous chunk of work ids -> same A-panel
    // stays XCD-local across its N-blocks.
    int nb = gridDim.x * gridDim.y;
    int p  = blockIdx.x + gridDim.x * blockIdx.y;
    int u = p & 7, i8 = p >> 3;
    int q8 = nb >> 3, r8 = nb & 7;
    int w = (u < r8 ? u * (q8 + 1) : r8 * (q8 + 1) + (u - r8) * q8) + i8;
    int bx = w % gridDim.x, by = w / gridDim.x;

    int m0 = by * 128, n0 = bx * 128;
    int wm = (wv >> 1) * 64, wn = (wv & 1) * 64;

    const int Ks = K / SPLIT;
    const int kbase = blockIdx.z * Ks;
    const int T = Ks / 32;

    f4v acc[4][4];
    const f4v zero = {0.f, 0.f, 0.f, 0.f};
#pragma unroll
    for (int i = 0; i < 4; ++i)
#pragma unroll
        for (int j = 0; j < 4; ++j) acc[i][j] = zero;

    // fragment-major staging: lane l of subtile g fetches global
    // (row g*16 + (l&15), k-chunk l>>4); DMA writes LDS at g*1024B + l*16B.
    auto stage = [&](int t, int bufi) {
#pragma unroll
        for (int gg = 0; gg < 2; ++gg) {
            int g = wv + gg * 4;                // subtile 0..7
            const unsigned short* ga =
                A + (size_t)(m0 + g * 16 + l16) * K + kbase + t * 32 + quad * 8;
            async16(&Al[bufi][g * 512], ga);
            const unsigned short* gb =
                Bt + (size_t)(n0 + g * 16 + l16) * K + kbase + t * 32 + quad * 8;
            async16(&Bl[bufi][g * 512], gb);
        }
    };

    auto compute = [&](int cur) {
        s8v af[4], bfr[4];
        int lo = lane * 8;                      // shorts: lane*16 B
#pragma unroll
        for (int i = 0; i < 4; ++i)
            af[i] = *reinterpret_cast<const s8v*>(&Al[cur][((wm >> 4) + i) * 512 + lo]);
#pragma unroll
        for (int j = 0; j < 4; ++j)
            bfr[j] = *reinterpret_cast<const s8v*>(&Bl[cur][((wn >> 4) + j) * 512 + lo]);
        __builtin_amdgcn_s_setprio(1);
#pragma unroll
        for (int i = 0; i < 4; ++i)
#pragma unroll
            for (int j = 0; j < 4; ++j)
                acc[i][j] = __builtin_amdgcn_mfma_f32_16x16x32_bf16(af[i], bfr[j], acc[i][j], 0, 0, 0);
        __builtin_amdgcn_s_setprio(0);
    };

    stage(0, 0);
    stage(1, 1);

    int cur = 0, pre = 2;
    for (int t = 0; t < T - 1; ++t) {
        // tile t's 4 DMAs are the oldest; tile t+1's 4 may stay in flight
        asm volatile("s_waitcnt vmcnt(4)" ::: "memory");
        __builtin_amdgcn_s_barrier();
        asm volatile("" ::: "memory");
        if (t + 2 < T) stage(t + 2, pre);
        compute(cur);
        cur = (cur == 2) ? 0 : cur + 1;
        pre = (pre == 2) ? 0 : pre + 1;
    }
    asm volatile("s_waitcnt vmcnt(0)" ::: "memory");
    __builtin_amdgcn_s_barrier();
    asm volatile("" ::: "memory");
    compute(cur);

    // epilogue: C/D layout col=lane&15, row=quad*4+reg
#pragma unroll
    for (int j = 0; j < 4; ++j) {
        int col = n0 + wn + j * 16 + l16;
        float bj = bias ? bias[col] : 0.f;
        if (SPLIT > 1 && blockIdx.z != 0) bj = 0.f;
#pragma unroll
        for (int i = 0; i < 4; ++i) {
#pragma unroll
            for (int r = 0; r < 4; ++r) {
                int row = m0 + wm + i * 16 + quad * 4 + r;
                if (row >= M) continue;
                float v = acc[i][j][r] + bj;
                size_t idx = (size_t)row * N + col;
                if (OP == 0) {
                    ((unsigned short*)Cv)[idx] = f2bfu(v);
                } else if (OP == 1) {
                    v = 0.5f * v * (1.f + erff(v * 0.70710678118654752f));
                    ((unsigned short*)Cv)[idx] = f2bfu(v);
                } else if (OP == 2) {
                    float* C = (float*)Cv;
                    if (SPLIT > 1) atomicAdd(&C[idx], v);
                    else C[idx] += v;
                } else if (OP == 3) {
                    ((float*)Cv)[idx] = v;
                } else {
                    float* base = (float*)((SPLIT > 2 && blockIdx.z >= 2) ? Cv2 : Cv);
                    float* C = base + (size_t)(blockIdx.z & 1) * ((size_t)M * N);
                    C[idx] = v;
                }
            }
        }
    }
}

// ---------------------------------------------------------------------------
// MFMA flash attention (bf16, fp32 softmax). One block per (b*h, q-tile 64).
// 4 waves; wave w owns queries q0+w*16..+15. No 1/sqrt(d) scale (faithful).
// ---------------------------------------------------------------------------
__global__ __launch_bounds__(256) void mattn_k(const unsigned short* __restrict__ qkv,
                                               unsigned short* __restrict__ o) {
    __shared__ unsigned short Kl[64 * 72];
    __shared__ unsigned short Vt[64 * 72];
    __shared__ unsigned short Pw[4][16 * 72];

    int tid = threadIdx.x;
    int w = tid >> 6, lane = tid & 63, quad = lane >> 4, l16 = lane & 15;
    int bh = blockIdx.x;
    int b = bh / HEADS, h = bh % HEADS;
    int q0 = blockIdx.y * 64;

    int qq = q0 + w * 16 + l16;
    if (qq > SS - 1) qq = SS - 1;
    const unsigned short* qp = qkv + (size_t)(b * SS + qq) * QW + h * DH + quad * 8;
    s8v aq0 = *reinterpret_cast<const s8v*>(qp);
    s8v aq1 = *reinterpret_cast<const s8v*>(qp + 32);

    float m[4], l[4];
    f4v O[4];
    const f4v zero = {0.f, 0.f, 0.f, 0.f};
#pragma unroll
    for (int r = 0; r < 4; ++r) { m[r] = -INFINITY; l[r] = 0.f; }
#pragma unroll
    for (int dg = 0; dg < 4; ++dg) O[dg] = zero;

    for (int t = 0; t < NKT; ++t) {
        int k0 = t * 64;
        __syncthreads();
#pragma unroll
        for (int rr = 0; rr < 2; ++rr) {
            int cid = tid + rr * 256;
            int row = cid >> 3, cb = (cid & 7) * 8;
            s8v kv = *reinterpret_cast<const s8v*>(
                qkv + (size_t)(b * SS + k0 + row) * QW + DIM + h * DH + cb);
            *reinterpret_cast<s8v*>(&Kl[row * 72 + cb]) = kv;
        }
        {
            int kb = (tid & 15) * 4, db = (tid >> 4) * 4;
            const unsigned short* vb = qkv + (size_t)(b * SS + k0 + kb) * QW + 2 * DIM + h * DH + db;
            ushort4 r0 = *reinterpret_cast<const ushort4*>(vb);
            ushort4 r1 = *reinterpret_cast<const ushort4*>(vb + QW);
            ushort4 r2 = *reinterpret_cast<const ushort4*>(vb + 2 * QW);
            ushort4 r3 = *reinterpret_cast<const ushort4*>(vb + 3 * QW);
            ushort4 w0 = {r0.x, r1.x, r2.x, r3.x};
            ushort4 w1 = {r0.y, r1.y, r2.y, r3.y};
            ushort4 w2 = {r0.z, r1.z, r2.z, r3.z};
            ushort4 w3 = {r0.w, r1.w, r2.w, r3.w};
            *reinterpret_cast<ushort4*>(&Vt[(db + 0) * 72 + kb]) = w0;
            *reinterpret_cast<ushort4*>(&Vt[(db + 1) * 72 + kb]) = w1;
            *reinterpret_cast<ushort4*>(&Vt[(db + 2) * 72 + kb]) = w2;
            *reinterpret_cast<ushort4*>(&Vt[(db + 3) * 72 + kb]) = w3;
        }
        __syncthreads();

        f4v s[4];
#pragma unroll
        for (int kk = 0; kk < 4; ++kk) {
            const unsigned short* kp = &Kl[(kk * 16 + l16) * 72 + quad * 8];
            s8v b0 = *reinterpret_cast<const s8v*>(kp);
            s8v b1 = *reinterpret_cast<const s8v*>(kp + 32);
            f4v z = zero;
            z = __builtin_amdgcn_mfma_f32_16x16x32_bf16(aq0, b0, z, 0, 0, 0);
            z = __builtin_amdgcn_mfma_f32_16x16x32_bf16(aq1, b1, z, 0, 0, 0);
            s[kk] = z;
        }
        int kvalid = SS - k0;
        if (kvalid < 64) {
#pragma unroll
            for (int kk = 0; kk < 4; ++kk)
                if (kk * 16 + l16 >= kvalid) {
                    f4v mk = {-1e30f, -1e30f, -1e30f, -1e30f};
                    s[kk] = mk;
                }
        }
        float alpha[4];
#pragma unroll
        for (int r = 0; r < 4; ++r) {
            float mx = fmaxf(fmaxf(s[0][r], s[1][r]), fmaxf(s[2][r], s[3][r]));
#pragma unroll
            for (int off = 1; off < 16; off <<= 1) mx = fmaxf(mx, __shfl_xor(mx, off));
            float mn = fmaxf(m[r], mx);
            alpha[r] = __expf(m[r] - mn);
            m[r] = mn;
            float ps = 0.f;
#pragma unroll
            for (int kk = 0; kk < 4; ++kk) {
                float p = __expf(s[kk][r] - mn);
                ps += p;
                Pw[w][(quad * 4 + r) * 72 + kk * 16 + l16] = f2bfu(p);
            }
#pragma unroll
            for (int off = 1; off < 16; off <<= 1) ps += __shfl_xor(ps, off);
            l[r] = l[r] * alpha[r] + ps;
        }
#pragma unroll
        for (int dg = 0; dg < 4; ++dg)
#pragma unroll
            for (int r = 0; r < 4; ++r) O[dg][r] *= alpha[r];

        s8v ap0 = *reinterpret_cast<const s8v*>(&Pw[w][l16 * 72 + quad * 8]);
        s8v ap1 = *reinterpret_cast<const s8v*>(&Pw[w][l16 * 72 + 32 + quad * 8]);
#pragma unroll
        for (int dg = 0; dg < 4; ++dg) {
            const unsigned short* vp = &Vt[(dg * 16 + l16) * 72 + quad * 8];
            s8v bv0 = *reinterpret_cast<const s8v*>(vp);
            s8v bv1 = *reinterpret_cast<const s8v*>(vp + 32);
            O[dg] = __builtin_amdgcn_mfma_f32_16x16x32_bf16(ap0, bv0, O[dg], 0, 0, 0);
            O[dg] = __builtin_amdgcn_mfma_f32_16x16x32_bf16(ap1, bv1, O[dg], 0, 0, 0);
        }
    }

#pragma unroll
    for (int r = 0; r < 4; ++r) {
        int q = q0 + w * 16 + quad * 4 + r;
        if (q >= SS) continue;
        float inv = 1.f / l[r];
        unsigned short* op = o + (size_t)(b * SS + q) * DIM + h * DH + l16;
#pragma unroll
        for (int dg = 0; dg < 4; ++dg)
            op[dg * 16] = f2bfu(O[dg][r] * inv);
    }
}

// ---------------------------------------------------------------------------
// Output: x[:, 1:, :] (+ optional partial slices) fp32 -> out (B, NP, DIM)
// ---------------------------------------------------------------------------
template <int NPART>
__global__ __launch_bounds__(256) void copy_out_k(const float* __restrict__ x,
                                                  const float* __restrict__ P,
                                                  const float* __restrict__ P2,
                                                  float* __restrict__ out) {
    int idx = blockIdx.x * 256 + threadIdx.x;
    const int total = BB * NP * DIM;
    if (idx >= total) return;
    int b = idx / (NP * DIM);
    int r = idx % (NP * DIM);
    int n = r / DIM;
    int d = r % DIM;
    size_t row = (size_t)b * SS + 1 + n;
    float v = x[row * DIM + d];
    if (NPART >= 2)
        v += P[row * DIM + d] + P[(size_t)BS * DIM + row * DIM + d];
    if (NPART == 4)
        v += P2[row * DIM + d] + P2[(size_t)BS * DIM + row * DIM + d];
    out[idx] = v;
}

// ---------------------------------------------------------------------------
extern "C" void kernel_launch(void* const* d_in, const int* in_sizes, int n_in,
                              void* d_out, int out_size, void* d_ws, size_t ws_size,
                              hipStream_t stream) {
    const float* img     = (const float*)d_in[0];
    const float* pos     = (const float*)d_in[1];
    const float* cls     = (const float*)d_in[2];
    const float* patch_w = (const float*)d_in[3];
    const float* patch_b = (const float*)d_in[4];
    const float* ln1_g   = (const float*)d_in[5];
    const float* ln1_b   = (const float*)d_in[6];
    const float* qkv_w   = (const float*)d_in[7];
    const float* out_w   = (const float*)d_in[8];
    const float* out_b   = (const float*)d_in[9];
    const float* ln2_g   = (const float*)d_in[10];
    const float* ln2_b   = (const float*)d_in[11];
    const float* ff1_w   = (const float*)d_in[12];
    const float* ff1_b   = (const float*)d_in[13];
    const float* ff2_w   = (const float*)d_in[14];
    const float* ff2_b   = (const float*)d_in[15];
    float* out = (float*)d_out;

    // workspace layout
    char* base = (char*)d_ws;
    float* x = (float*)base;                          base += (size_t)BS * DIM * 4;
    unsigned short* y_bf   = (unsigned short*)base;   base += (size_t)MPAD * DIM * 2;
    unsigned short* t1_bf  = (unsigned short*)base;   base += (size_t)MPAD * DIM * 2;
    unsigned short* qkv_bf = (unsigned short*)base;   base += (size_t)MPAD * 3 * DIM * 2;
    unsigned short* hid_bf = (unsigned short*)base;   base += (size_t)MPAD * MLP * 2;
    unsigned short* xp_bf  = (unsigned short*)base;   base += (size_t)BB * NP * PD * 2;
    // per-layer transposed bf16 weights
    unsigned short* wq_t = (unsigned short*)base;     base += (size_t)(3 * DIM) * DIM * 2;
    unsigned short* wo_t = (unsigned short*)base;     base += (size_t)DIM * DIM * 2;
    unsigned short* w1_t = (unsigned short*)base;     base += (size_t)MLP * DIM * 2;
    unsigned short* w2_t = (unsigned short*)base;     base += (size_t)DIM * MLP * 2;
    // 2-slice fp32 split-K partial buffer (slices 0,1)
    float* part = (float*)base;                       base += (size_t)2 * BS * DIM * 4;
    // slices 2,3 alias t1_bf+qkv_bf (7.3+21.8 MB >= 28.4 MB), both dead when
    // ff2 runs (t1 last read: attn-out GEMM; qkv last read: mattn), and
    // consumed by ln1/copy_out before qkv_bf is rewritten next layer.
    float* part23 = (float*)t1_bf;
    float* pe_f32 = (float*)hid_bf;   // patch-embed fp32 out, alias (consumed pre-loop)

    const int threads = 256;
    const int mblk = (BS + 127) / 128;   // 37

    patchify_k<<<(BB * NP * PD + 255) / 256, threads, 0, stream>>>(img, xp_bf);
    convT_k<<<dim3(DIM / 32, PD / 32), threads, 0, stream>>>(patch_w, wq_t, PD, DIM);
    mgemm_k<3, 1><<<dim3(DIM / 128, (BB * NP) / 128), threads, 0, stream>>>(
        xp_bf, wq_t, patch_b, pe_f32, nullptr, BB * NP, DIM, PD);
    build_x_k<<<(BB * SS * DIM + 255) / 256, threads, 0, stream>>>(pe_f32, cls, pos, x);

    for (int l = 0; l < DEPTH; ++l) {
        // ln1: layer 0 plain; later layers fold in previous ff2's 4 partials
        if (l == 0)
            ln_k<0><<<BS, threads, 0, stream>>>(x, nullptr, nullptr, ln1_g, ln1_b,
                                                y_bf, nullptr);
        else
            ln_k<4><<<BS, threads, 0, stream>>>(x, part, part23,
                                                ln1_g + l * DIM, ln1_b + l * DIM,
                                                y_bf, x);
        // all 4 weight conversions for this layer, one launch
        convT4_k<<<6912, threads, 0, stream>>>(
            qkv_w + (size_t)l * DIM * 3 * DIM,
            out_w + (size_t)l * DIM * DIM,
            ff1_w + (size_t)l * DIM * MLP,
            ff2_w + (size_t)l * MLP * DIM,
            wq_t, wo_t, w1_t, w2_t);
        mgemm_k<0, 1><<<dim3(3 * DIM / 128, mblk), threads, 0, stream>>>(
            y_bf, wq_t, nullptr, qkv_bf, nullptr, BS, 3 * DIM, DIM);
        // MFMA flash attention -> t1
        mattn_k<<<dim3(BB * HEADS, NKT), threads, 0, stream>>>(qkv_bf, t1_bf);
        // attn-out: split-K x2 partial stores; reduced inside ln2
        mgemm_k<4, 2><<<dim3(DIM / 128, mblk, 2), threads, 0, stream>>>(
            t1_bf, wo_t, out_b + l * DIM, part, nullptr, BS, DIM, DIM);
        // ln2: x += attn partials, then LN
        ln_k<2><<<BS, threads, 0, stream>>>(x, part, nullptr,
                                            ln2_g + l * DIM, ln2_b + l * DIM,
                                            y_bf, x);
        mgemm_k<1, 1><<<dim3(MLP / 128, mblk), threads, 0, stream>>>(
            y_bf, w1_t, ff1_b + l * MLP, hid_bf, nullptr, BS, MLP, DIM);
        // ff2: split-K x4 partial stores (888 blocks); reduced in next ln1
        mgemm_k<4, 4><<<dim3(DIM / 128, mblk, 4), threads, 0, stream>>>(
            hid_bf, w2_t, ff2_b + l * DIM, part, part23, BS, DIM, MLP);
    }

    copy_out_k<4><<<(BB * NP * DIM + 255) / 256, threads, 0, stream>>>(x, part, part23, out);
}

// Round 4
// 1821.424 us; speedup vs baseline: 1.2781x; 1.2781x over previous
//
#include <hip/hip_runtime.h>
#include <hip/hip_bf16.h>
#include <math.h>

// Problem constants (ViT): B=8, C=3, H=384, P=16 -> 24x24=576 patches, S=577
#define BB 8
#define CC 3
#define HH 384
#define PP 16
#define HP 24            // H/P
#define NP 576           // patches per image
#define PD 768           // patch dim = C*P*P
#define DIM 768
#define DEPTH 8
#define HEADS 12
#define DH 64            // DIM/HEADS
#define MLP 3072
#define SS 577           // seq len = NP+1
#define BS (BB*SS)       // 4616 rows
#define MPAD 4736        // 37*128, padded row count for GEMM A-operands
#define LN_EPS 1e-5f
#define NKT 10           // ceil(577/64) key tiles
#define QW (3*DIM)       // qkv row width 2304

typedef __attribute__((ext_vector_type(8))) short s8v;   // 8 bf16 = 4 VGPRs
typedef __attribute__((ext_vector_type(4))) float f4v;   // MFMA accum

__device__ __forceinline__ float bf2f(unsigned short s) {
    union { unsigned u; float f; } x;
    x.u = ((unsigned)s) << 16;
    return x.f;
}
__device__ __forceinline__ unsigned short f2bfu(float f) {
    __hip_bfloat16 h = __float2bfloat16(f);
    return *reinterpret_cast<unsigned short*>(&h);
}

// async global->LDS, 16B per lane; LDS dest = base + lane*16 (wave-uniform base)
__device__ __forceinline__ void async16(void* lds, const void* g) {
    __builtin_amdgcn_global_load_lds(
        (const __attribute__((address_space(1))) void*)(uintptr_t)g,
        (__attribute__((address_space(3))) void*)(unsigned)(uintptr_t)lds,
        16, 0, 0);
}

// ---------------------------------------------------------------------------
// Patchify: img (B,C,H,H) -> Xp_bf (B*NP, PD) bf16, vec index (p1*P+p2)*C + c
// ---------------------------------------------------------------------------
__global__ __launch_bounds__(256) void patchify_k(const float* __restrict__ img,
                                                  unsigned short* __restrict__ xp) {
    int idx = blockIdx.x * 256 + threadIdx.x;
    const int total = BB * NP * PD;
    if (idx >= total) return;
    int b = idx / (NP * PD);
    int r = idx % (NP * PD);
    int n = r / PD;
    int j = r % PD;
    int c  = j % CC;
    int t  = j / CC;
    int p2 = t % PP;
    int p1 = t / PP;
    int hh = n / HP;
    int ww = n % HP;
    int row = hh * PP + p1;
    int col = ww * PP + p2;
    xp[idx] = f2bfu(img[(((size_t)b * CC + c) * HH + row) * HH + col]);
}

// ---------------------------------------------------------------------------
// Weight convert + transpose: W (K,N) fp32 -> Wt (N,K) bf16.  K,N % 32 == 0.
// ---------------------------------------------------------------------------
__global__ __launch_bounds__(256) void convT_k(const float* __restrict__ W,
                                               unsigned short* __restrict__ Wt,
                                               int K, int N) {
    __shared__ float t[32][33];
    int tx = threadIdx.x & 31, ty = threadIdx.x >> 5;   // 32 x 8
    int n0 = blockIdx.x * 32, k0 = blockIdx.y * 32;
#pragma unroll
    for (int i = 0; i < 32; i += 8)
        t[ty + i][tx] = W[(size_t)(k0 + ty + i) * N + n0 + tx];
    __syncthreads();
#pragma unroll
    for (int i = 0; i < 32; i += 8)
        Wt[(size_t)(n0 + ty + i) * K + k0 + tx] = f2bfu(t[tx][ty + i]);
}

// ---------------------------------------------------------------------------
// Fused per-layer weight conversion: all 4 weights of one layer in one launch.
// Tile ranges (32x32 tiles): qkv (768,2304)=1728, out (768,768)=576,
// ff1 (768,3072)=2304, ff2 (3072,768)=2304 -> 6912 blocks total.
// ---------------------------------------------------------------------------
__global__ __launch_bounds__(256) void convT4_k(const float* __restrict__ s0,
                                                const float* __restrict__ s1,
                                                const float* __restrict__ s2,
                                                const float* __restrict__ s3,
                                                unsigned short* __restrict__ d0,
                                                unsigned short* __restrict__ d1,
                                                unsigned short* __restrict__ d2,
                                                unsigned short* __restrict__ d3) {
    __shared__ float t[32][33];
    int bid = blockIdx.x;
    const float* S; unsigned short* D; int K, N, lt;
    if (bid < 1728)      { S = s0; D = d0; K = 768;  N = 2304; lt = bid; }
    else if (bid < 2304) { S = s1; D = d1; K = 768;  N = 768;  lt = bid - 1728; }
    else if (bid < 4608) { S = s2; D = d2; K = 768;  N = 3072; lt = bid - 2304; }
    else                 { S = s3; D = d3; K = 3072; N = 768;  lt = bid - 4608; }
    int ntn = N >> 5;
    int n0 = (lt % ntn) * 32, k0 = (lt / ntn) * 32;
    int tx = threadIdx.x & 31, ty = threadIdx.x >> 5;   // 32 x 8
#pragma unroll
    for (int i = 0; i < 32; i += 8)
        t[ty + i][tx] = S[(size_t)(k0 + ty + i) * N + n0 + tx];
    __syncthreads();
#pragma unroll
    for (int i = 0; i < 32; i += 8)
        D[(size_t)(n0 + ty + i) * K + k0 + tx] = f2bfu(t[tx][ty + i]);
}

// ---------------------------------------------------------------------------
// Build residual stream x (B,S,DIM) fp32
// ---------------------------------------------------------------------------
__global__ __launch_bounds__(256) void build_x_k(const float* __restrict__ pe,
                                                 const float* __restrict__ cls,
                                                 const float* __restrict__ pos,
                                                 float* __restrict__ x) {
    int idx = blockIdx.x * 256 + threadIdx.x;
    const int total = BB * SS * DIM;
    if (idx >= total) return;
    int b = idx / (SS * DIM);
    int r = idx % (SS * DIM);
    int i = r / DIM;
    int d = r % DIM;
    float p = pos[i * DIM + d];
    float v = (i == 0) ? cls[d] : pe[((size_t)b * NP + (i - 1)) * DIM + d];
    x[idx] = v + p;
}

// ---------------------------------------------------------------------------
// LayerNorm (+ optional 2-slice partial-sum residual add): one block per row.
// NPART==0: y = LN(x)            (x untouched)
// NPART==2: xn = x + P0 + P1; store xn to x; y = LN(xn)
// Partial slice stride is BS*DIM floats.
// ---------------------------------------------------------------------------
template <int NPART>
__global__ __launch_bounds__(256) void ln_k(const float* __restrict__ x,
                                            const float* __restrict__ P,
                                            const float* __restrict__ g,
                                            const float* __restrict__ bt,
                                            unsigned short* __restrict__ y,
                                            float* __restrict__ xout) {
    __shared__ float sm[8];
    int row = blockIdx.x, tid = threadIdx.x;
    const float* xr = x + (size_t)row * DIM;
    float v0 = xr[tid], v1 = xr[tid + 256], v2 = xr[tid + 512];
    if (NPART == 2) {
        const float* p0 = P + (size_t)row * DIM;
        const float* p1 = P + (size_t)(BS + row) * DIM;
        v0 += p0[tid]       + p1[tid];
        v1 += p0[tid + 256] + p1[tid + 256];
        v2 += p0[tid + 512] + p1[tid + 512];
        float* xo = xout + (size_t)row * DIM;
        xo[tid] = v0; xo[tid + 256] = v1; xo[tid + 512] = v2;
    }
    float s = v0 + v1 + v2;
    for (int o = 32; o; o >>= 1) s += __shfl_xor(s, o);
    if ((tid & 63) == 0) sm[tid >> 6] = s;
    __syncthreads();
    float mean = (sm[0] + sm[1] + sm[2] + sm[3]) * (1.f / 768.f);
    float q0 = v0 - mean, q1 = v1 - mean, q2 = v2 - mean;
    float s2 = q0 * q0 + q1 * q1 + q2 * q2;
    for (int o = 32; o; o >>= 1) s2 += __shfl_xor(s2, o);
    if ((tid & 63) == 0) sm[4 + (tid >> 6)] = s2;
    __syncthreads();
    float var = (sm[4] + sm[5] + sm[6] + sm[7]) * (1.f / 768.f);
    float rstd = rsqrtf(var + LN_EPS);
    unsigned short* yr = y + (size_t)row * DIM;
    yr[tid]       = f2bfu(q0 * rstd * g[tid]       + bt[tid]);
    yr[tid + 256] = f2bfu(q1 * rstd * g[tid + 256] + bt[tid + 256]);
    yr[tid + 512] = f2bfu(q2 * rstd * g[tid + 512] + bt[tid + 512]);
}

// ---------------------------------------------------------------------------
// bf16 MFMA GEMM v5: 8 waves / 512 threads on a 128x128 tile (wave grid
// 2M x 4N, each wave owns 64x32 -> acc[4][2]). Latency-bound fix: doubles
// resident waves/SIMD (~2 -> ~4) and halves each wave's per-step chain
// (6 ds_read + 8 MFMA + 2 DMA). 3-buffer LDS, counted vmcnt(2) so next
// tile's DMAs stay in flight across the barrier; setprio around MFMAs.
// Staging is the proven coalesced row-major pattern (4 lanes = 64B row run).
//   A:  (Mpad, K) bf16 row-major; Bt: (N, K) bf16 row-major
//   OP 0: bf16 out = acc + bias      (bias may be null)
//   OP 1: bf16 out = gelu(acc+bias)
//   OP 2: fp32 C += acc + bias
//   OP 3: fp32 out = acc + bias
//   OP 4: fp32 partial store: C[z*M*N + idx] = acc (+bias only on z==0)
// ---------------------------------------------------------------------------
template <int OP, int SPLIT>
__global__ __launch_bounds__(512) void mgemm_k(const unsigned short* __restrict__ A,
                                               const unsigned short* __restrict__ Bt,
                                               const float* __restrict__ bias,
                                               void* __restrict__ Cv,
                                               int M, int N, int K) {
    __shared__ unsigned short Al[3][128 * 32];
    __shared__ unsigned short Bl[3][128 * 32];
    int tid = threadIdx.x;
    int wv = tid >> 6, lane = tid & 63;
    int quad = lane >> 4, l16 = lane & 15;
    int m0 = blockIdx.y * 128, n0 = blockIdx.x * 128;
    int wm = (wv >> 2) * 64, wn = (wv & 3) * 32;   // 2M x 4N wave grid
    int rg = lane >> 2;            // row within 16-row staging group
    int kc = (lane & 3) * 8;       // k element offset (8 bf16 = 16B)

    const int Ks = K / SPLIT;
    const int kbase = blockIdx.z * Ks;
    const int T = Ks / 32;

    f4v acc[4][2];
    const f4v zero = {0.f, 0.f, 0.f, 0.f};
#pragma unroll
    for (int i = 0; i < 4; ++i)
#pragma unroll
        for (int j = 0; j < 2; ++j) acc[i][j] = zero;

    // wave wv stages subtile wv of A and of B (1 async16 each)
    auto stage = [&](int t, int bufi) {
        const unsigned short* ga =
            A + (size_t)(m0 + wv * 16 + rg) * K + kbase + t * 32 + kc;
        async16(&Al[bufi][wv * 512], ga);
        const unsigned short* gb =
            Bt + (size_t)(n0 + wv * 16 + rg) * K + kbase + t * 32 + kc;
        async16(&Bl[bufi][wv * 512], gb);
    };

    auto compute = [&](int cur) {
        s8v af[4], bfr[2];
#pragma unroll
        for (int i = 0; i < 4; ++i)
            af[i] = *reinterpret_cast<const s8v*>(&Al[cur][(wm + i * 16 + l16) * 32 + quad * 8]);
#pragma unroll
        for (int j = 0; j < 2; ++j)
            bfr[j] = *reinterpret_cast<const s8v*>(&Bl[cur][(wn + j * 16 + l16) * 32 + quad * 8]);
        __builtin_amdgcn_s_setprio(1);
#pragma unroll
        for (int i = 0; i < 4; ++i)
#pragma unroll
            for (int j = 0; j < 2; ++j)
                acc[i][j] = __builtin_amdgcn_mfma_f32_16x16x32_bf16(af[i], bfr[j], acc[i][j], 0, 0, 0);
        __builtin_amdgcn_s_setprio(0);
    };

    stage(0, 0);
    stage(1, 1);

    int cur = 0, pre = 2;
    for (int t = 0; t < T - 1; ++t) {
        // tile t's 2 DMAs are the oldest; tile t+1's 2 may stay in flight
        asm volatile("s_waitcnt vmcnt(2)" ::: "memory");
        __builtin_amdgcn_s_barrier();
        asm volatile("" ::: "memory");
        if (t + 2 < T) stage(t + 2, pre);
        compute(cur);
        cur = (cur == 2) ? 0 : cur + 1;
        pre = (pre == 2) ? 0 : pre + 1;
    }
    asm volatile("s_waitcnt vmcnt(0)" ::: "memory");
    __builtin_amdgcn_s_barrier();
    asm volatile("" ::: "memory");
    compute(cur);

    // epilogue: C/D layout col=lane&15, row=quad*4+reg
#pragma unroll
    for (int j = 0; j < 2; ++j) {
        int col = n0 + wn + j * 16 + l16;
        float bj = bias ? bias[col] : 0.f;
        if (SPLIT > 1 && blockIdx.z != 0) bj = 0.f;
#pragma unroll
        for (int i = 0; i < 4; ++i) {
#pragma unroll
            for (int r = 0; r < 4; ++r) {
                int row = m0 + wm + i * 16 + quad * 4 + r;
                if (row >= M) continue;
                float v = acc[i][j][r] + bj;
                size_t idx = (size_t)row * N + col;
                if (OP == 0) {
                    ((unsigned short*)Cv)[idx] = f2bfu(v);
                } else if (OP == 1) {
                    v = 0.5f * v * (1.f + erff(v * 0.70710678118654752f));
                    ((unsigned short*)Cv)[idx] = f2bfu(v);
                } else if (OP == 2) {
                    float* C = (float*)Cv;
                    if (SPLIT > 1) atomicAdd(&C[idx], v);
                    else C[idx] += v;
                } else if (OP == 3) {
                    ((float*)Cv)[idx] = v;
                } else {
                    float* C = (float*)Cv + (size_t)blockIdx.z * ((size_t)M * N);
                    C[idx] = v;
                }
            }
        }
    }
}

// ---------------------------------------------------------------------------
// MFMA flash attention (bf16, fp32 softmax). One block per (b*h, q-tile 64).
// 4 waves; wave w owns queries q0+w*16..+15. No 1/sqrt(d) scale (faithful).
// ---------------------------------------------------------------------------
__global__ __launch_bounds__(256) void mattn_k(const unsigned short* __restrict__ qkv,
                                               unsigned short* __restrict__ o) {
    __shared__ unsigned short Kl[64 * 72];
    __shared__ unsigned short Vt[64 * 72];
    __shared__ unsigned short Pw[4][16 * 72];

    int tid = threadIdx.x;
    int w = tid >> 6, lane = tid & 63, quad = lane >> 4, l16 = lane & 15;
    int bh = blockIdx.x;
    int b = bh / HEADS, h = bh % HEADS;
    int q0 = blockIdx.y * 64;

    int qq = q0 + w * 16 + l16;
    if (qq > SS - 1) qq = SS - 1;
    const unsigned short* qp = qkv + (size_t)(b * SS + qq) * QW + h * DH + quad * 8;
    s8v aq0 = *reinterpret_cast<const s8v*>(qp);
    s8v aq1 = *reinterpret_cast<const s8v*>(qp + 32);

    float m[4], l[4];
    f4v O[4];
    const f4v zero = {0.f, 0.f, 0.f, 0.f};
#pragma unroll
    for (int r = 0; r < 4; ++r) { m[r] = -INFINITY; l[r] = 0.f; }
#pragma unroll
    for (int dg = 0; dg < 4; ++dg) O[dg] = zero;

    for (int t = 0; t < NKT; ++t) {
        int k0 = t * 64;
        __syncthreads();
#pragma unroll
        for (int rr = 0; rr < 2; ++rr) {
            int cid = tid + rr * 256;
            int row = cid >> 3, cb = (cid & 7) * 8;
            s8v kv = *reinterpret_cast<const s8v*>(
                qkv + (size_t)(b * SS + k0 + row) * QW + DIM + h * DH + cb);
            *reinterpret_cast<s8v*>(&Kl[row * 72 + cb]) = kv;
        }
        {
            int kb = (tid & 15) * 4, db = (tid >> 4) * 4;
            const unsigned short* vb = qkv + (size_t)(b * SS + k0 + kb) * QW + 2 * DIM + h * DH + db;
            ushort4 r0 = *reinterpret_cast<const ushort4*>(vb);
            ushort4 r1 = *reinterpret_cast<const ushort4*>(vb + QW);
            ushort4 r2 = *reinterpret_cast<const ushort4*>(vb + 2 * QW);
            ushort4 r3 = *reinterpret_cast<const ushort4*>(vb + 3 * QW);
            ushort4 w0 = {r0.x, r1.x, r2.x, r3.x};
            ushort4 w1 = {r0.y, r1.y, r2.y, r3.y};
            ushort4 w2 = {r0.z, r1.z, r2.z, r3.z};
            ushort4 w3 = {r0.w, r1.w, r2.w, r3.w};
            *reinterpret_cast<ushort4*>(&Vt[(db + 0) * 72 + kb]) = w0;
            *reinterpret_cast<ushort4*>(&Vt[(db + 1) * 72 + kb]) = w1;
            *reinterpret_cast<ushort4*>(&Vt[(db + 2) * 72 + kb]) = w2;
            *reinterpret_cast<ushort4*>(&Vt[(db + 3) * 72 + kb]) = w3;
        }
        __syncthreads();

        f4v s[4];
#pragma unroll
        for (int kk = 0; kk < 4; ++kk) {
            const unsigned short* kp = &Kl[(kk * 16 + l16) * 72 + quad * 8];
            s8v b0 = *reinterpret_cast<const s8v*>(kp);
            s8v b1 = *reinterpret_cast<const s8v*>(kp + 32);
            f4v z = zero;
            z = __builtin_amdgcn_mfma_f32_16x16x32_bf16(aq0, b0, z, 0, 0, 0);
            z = __builtin_amdgcn_mfma_f32_16x16x32_bf16(aq1, b1, z, 0, 0, 0);
            s[kk] = z;
        }
        int kvalid = SS - k0;
        if (kvalid < 64) {
#pragma unroll
            for (int kk = 0; kk < 4; ++kk)
                if (kk * 16 + l16 >= kvalid) {
                    f4v mk = {-1e30f, -1e30f, -1e30f, -1e30f};
                    s[kk] = mk;
                }
        }
        float alpha[4];
#pragma unroll
        for (int r = 0; r < 4; ++r) {
            float mx = fmaxf(fmaxf(s[0][r], s[1][r]), fmaxf(s[2][r], s[3][r]));
#pragma unroll
            for (int off = 1; off < 16; off <<= 1) mx = fmaxf(mx, __shfl_xor(mx, off));
            float mn = fmaxf(m[r], mx);
            alpha[r] = __expf(m[r] - mn);
            m[r] = mn;
            float ps = 0.f;
#pragma unroll
            for (int kk = 0; kk < 4; ++kk) {
                float p = __expf(s[kk][r] - mn);
                ps += p;
                Pw[w][(quad * 4 + r) * 72 + kk * 16 + l16] = f2bfu(p);
            }
#pragma unroll
            for (int off = 1; off < 16; off <<= 1) ps += __shfl_xor(ps, off);
            l[r] = l[r] * alpha[r] + ps;
        }
#pragma unroll
        for (int dg = 0; dg < 4; ++dg)
#pragma unroll
            for (int r = 0; r < 4; ++r) O[dg][r] *= alpha[r];

        s8v ap0 = *reinterpret_cast<const s8v*>(&Pw[w][l16 * 72 + quad * 8]);
        s8v ap1 = *reinterpret_cast<const s8v*>(&Pw[w][l16 * 72 + 32 + quad * 8]);
#pragma unroll
        for (int dg = 0; dg < 4; ++dg) {
            const unsigned short* vp = &Vt[(dg * 16 + l16) * 72 + quad * 8];
            s8v bv0 = *reinterpret_cast<const s8v*>(vp);
            s8v bv1 = *reinterpret_cast<const s8v*>(vp + 32);
            O[dg] = __builtin_amdgcn_mfma_f32_16x16x32_bf16(ap0, bv0, O[dg], 0, 0, 0);
            O[dg] = __builtin_amdgcn_mfma_f32_16x16x32_bf16(ap1, bv1, O[dg], 0, 0, 0);
        }
    }

#pragma unroll
    for (int r = 0; r < 4; ++r) {
        int q = q0 + w * 16 + quad * 4 + r;
        if (q >= SS) continue;
        float inv = 1.f / l[r];
        unsigned short* op = o + (size_t)(b * SS + q) * DIM + h * DH + l16;
#pragma unroll
        for (int dg = 0; dg < 4; ++dg)
            op[dg * 16] = f2bfu(O[dg][r] * inv);
    }
}

// ---------------------------------------------------------------------------
// Output: x[:, 1:, :] (+ optional 2 partial slices) fp32 -> out (B, NP, DIM)
// ---------------------------------------------------------------------------
template <int NPART>
__global__ __launch_bounds__(256) void copy_out_k(const float* __restrict__ x,
                                                  const float* __restrict__ P,
                                                  float* __restrict__ out) {
    int idx = blockIdx.x * 256 + threadIdx.x;
    const int total = BB * NP * DIM;
    if (idx >= total) return;
    int b = idx / (NP * DIM);
    int r = idx % (NP * DIM);
    int n = r / DIM;
    int d = r % DIM;
    size_t row = (size_t)b * SS + 1 + n;
    float v = x[row * DIM + d];
    if (NPART == 2)
        v += P[row * DIM + d] + P[(size_t)BS * DIM + row * DIM + d];
    out[idx] = v;
}

// ---------------------------------------------------------------------------
extern "C" void kernel_launch(void* const* d_in, const int* in_sizes, int n_in,
                              void* d_out, int out_size, void* d_ws, size_t ws_size,
                              hipStream_t stream) {
    const float* img     = (const float*)d_in[0];
    const float* pos     = (const float*)d_in[1];
    const float* cls     = (const float*)d_in[2];
    const float* patch_w = (const float*)d_in[3];
    const float* patch_b = (const float*)d_in[4];
    const float* ln1_g   = (const float*)d_in[5];
    const float* ln1_b   = (const float*)d_in[6];
    const float* qkv_w   = (const float*)d_in[7];
    const float* out_w   = (const float*)d_in[8];
    const float* out_b   = (const float*)d_in[9];
    const float* ln2_g   = (const float*)d_in[10];
    const float* ln2_b   = (const float*)d_in[11];
    const float* ff1_w   = (const float*)d_in[12];
    const float* ff1_b   = (const float*)d_in[13];
    const float* ff2_w   = (const float*)d_in[14];
    const float* ff2_b   = (const float*)d_in[15];
    float* out = (float*)d_out;

    // workspace layout
    char* base = (char*)d_ws;
    float* x = (float*)base;                          base += (size_t)BS * DIM * 4;
    unsigned short* y_bf   = (unsigned short*)base;   base += (size_t)MPAD * DIM * 2;
    unsigned short* t1_bf  = (unsigned short*)base;   base += (size_t)MPAD * DIM * 2;
    unsigned short* qkv_bf = (unsigned short*)base;   base += (size_t)MPAD * 3 * DIM * 2;
    unsigned short* hid_bf = (unsigned short*)base;   base += (size_t)MPAD * MLP * 2;
    unsigned short* xp_bf  = (unsigned short*)base;   base += (size_t)BB * NP * PD * 2;
    // per-layer transposed bf16 weights
    unsigned short* wq_t = (unsigned short*)base;     base += (size_t)(3 * DIM) * DIM * 2;
    unsigned short* wo_t = (unsigned short*)base;     base += (size_t)DIM * DIM * 2;
    unsigned short* w1_t = (unsigned short*)base;     base += (size_t)MLP * DIM * 2;
    unsigned short* w2_t = (unsigned short*)base;     base += (size_t)DIM * MLP * 2;
    // 2-slice fp32 split-K partial buffer
    float* part = (float*)base;                       base += (size_t)2 * BS * DIM * 4;
    float* pe_f32 = (float*)hid_bf;   // patch-embed fp32 out, alias (consumed pre-loop)

    const int threads = 256;
    const int gthreads = 512;            // 8-wave GEMM blocks
    const int mblk = (BS + 127) / 128;   // 37

    patchify_k<<<(BB * NP * PD + 255) / 256, threads, 0, stream>>>(img, xp_bf);
    convT_k<<<dim3(DIM / 32, PD / 32), threads, 0, stream>>>(patch_w, wq_t, PD, DIM);
    mgemm_k<3, 1><<<dim3(DIM / 128, (BB * NP) / 128), gthreads, 0, stream>>>(
        xp_bf, wq_t, patch_b, pe_f32, BB * NP, DIM, PD);
    build_x_k<<<(BB * SS * DIM + 255) / 256, threads, 0, stream>>>(pe_f32, cls, pos, x);

    for (int l = 0; l < DEPTH; ++l) {
        // ln1: layer 0 plain; later layers fold in previous ff2 partials
        if (l == 0)
            ln_k<0><<<BS, threads, 0, stream>>>(x, nullptr, ln1_g, ln1_b, y_bf, nullptr);
        else
            ln_k<2><<<BS, threads, 0, stream>>>(x, part, ln1_g + l * DIM, ln1_b + l * DIM,
                                                y_bf, x);
        // all 4 weight conversions for this layer, one launch
        convT4_k<<<6912, threads, 0, stream>>>(
            qkv_w + (size_t)l * DIM * 3 * DIM,
            out_w + (size_t)l * DIM * DIM,
            ff1_w + (size_t)l * DIM * MLP,
            ff2_w + (size_t)l * MLP * DIM,
            wq_t, wo_t, w1_t, w2_t);
        mgemm_k<0, 1><<<dim3(3 * DIM / 128, mblk), gthreads, 0, stream>>>(
            y_bf, wq_t, nullptr, qkv_bf, BS, 3 * DIM, DIM);
        // MFMA flash attention -> t1
        mattn_k<<<dim3(BB * HEADS, NKT), threads, 0, stream>>>(qkv_bf, t1_bf);
        // attn-out: split-K x2 partial stores (no atomics); reduced inside ln2
        mgemm_k<4, 2><<<dim3(DIM / 128, mblk, 2), gthreads, 0, stream>>>(
            t1_bf, wo_t, out_b + l * DIM, part, BS, DIM, DIM);
        // ln2: x += attn partials, then LN
        ln_k<2><<<BS, threads, 0, stream>>>(x, part, ln2_g + l * DIM, ln2_b + l * DIM,
                                            y_bf, x);
        mgemm_k<1, 1><<<dim3(MLP / 128, mblk), gthreads, 0, stream>>>(
            y_bf, w1_t, ff1_b + l * MLP, hid_bf, BS, MLP, DIM);
        // ff2: split-K x2 partial stores; reduced inside next ln1 (or copy_out)
        mgemm_k<4, 2><<<dim3(DIM / 128, mblk, 2), gthreads, 0, stream>>>(
            hid_bf, w2_t, ff2_b + l * DIM, part, BS, DIM, MLP);
    }

    copy_out_k<2><<<(BB * NP * DIM + 255) / 256, threads, 0, stream>>>(x, part, out);
}